// Round 1
// baseline (97.954 us; speedup 1.0000x reference)
//
#include <hip/hip_runtime.h>
#include <hip/hip_bf16.h>

typedef float v2f __attribute__((ext_vector_type(2)));
typedef float v4f __attribute__((ext_vector_type(4)));

#define DD 256   // input embed dim
#define HH 64    // hidden dim

// ---------------------------------------------------------------------------
// prep: blocks 0..127   -> U rows [16b, 16b+16) = ag @ W1[:256] + b1, row-major U[n][64]
//       blocks 128..255 -> V rows of ab         = ab @ W1[256:],      h-major V[h][2048]
// ---------------------------------------------------------------------------
__global__ __launch_bounds__(256) void prep_kernel(
    const float* __restrict__ ag, const float* __restrict__ ab,
    const float* __restrict__ W1, const float* __restrict__ b1,
    float* __restrict__ U, float* __restrict__ V)
{
    __shared__ float a_tile[16 * DD];   // 16 KB, A rows (row-major)
    __shared__ float w_tile[DD * HH];   // 64 KB, W half [k][h]

    const int t = threadIdx.x;
    const int b = blockIdx.x;
    const bool isV = (b >= 128);
    const float* __restrict__ A = isV ? ab : ag;
    const int row0 = (isV ? b - 128 : b) * 16;
    const float* __restrict__ W = W1 + (isV ? DD * HH : 0);

    // stage A tile (4096 floats) and W half (16384 floats), fully coalesced float4
    {
        const v4f* As = (const v4f*)(A + row0 * DD);
        v4f* Ad = (v4f*)a_tile;
        #pragma unroll
        for (int i = 0; i < 4; ++i) Ad[t + i * 256] = As[t + i * 256];
        const v4f* Ws = (const v4f*)W;
        v4f* Wd = (v4f*)w_tile;
        #pragma unroll
        for (int i = 0; i < 16; ++i) Wd[t + i * 256] = Ws[t + i * 256];
    }
    __syncthreads();

    // thread: h = t&63 (lane -> conflict-free w reads), 4 rows (wave-uniform -> broadcast a reads)
    const int h = t & 63;
    const int g = t >> 6;
    float acc0 = 0.f, acc1 = 0.f, acc2 = 0.f, acc3 = 0.f;
    const float* __restrict__ ar = a_tile + (g * 4) * DD;
    #pragma unroll 8
    for (int k = 0; k < DD; ++k) {
        const float w = w_tile[k * HH + h];
        acc0 += ar[k]          * w;
        acc1 += ar[k + DD]     * w;
        acc2 += ar[k + 2 * DD] * w;
        acc3 += ar[k + 3 * DD] * w;
    }

    if (!isV) {
        const float bb = b1[h];
        float* Ur = U + (row0 + g * 4) * HH + h;   // lanes h -> consecutive: coalesced
        Ur[0]      = acc0 + bb;
        Ur[HH]     = acc1 + bb;
        Ur[2 * HH] = acc2 + bb;
        Ur[3 * HH] = acc3 + bb;
    } else {
        // transpose 16x64 tile through LDS, then coalesced-ish float4 stores (h-major)
        __syncthreads();                 // everyone done reading a_tile
        float* buf = a_tile;             // reuse as [16][64]
        buf[(g * 4 + 0) * HH + h] = acc0;
        buf[(g * 4 + 1) * HH + h] = acc1;
        buf[(g * 4 + 2) * HH + h] = acc2;
        buf[(g * 4 + 3) * HH + h] = acc3;
        __syncthreads();
        const int hs = t >> 2, q = t & 3;
        v4f f;
        f.x = buf[(q * 4 + 0) * HH + hs];
        f.y = buf[(q * 4 + 1) * HH + hs];
        f.z = buf[(q * 4 + 2) * HH + hs];
        f.w = buf[(q * 4 + 3) * HH + hs];
        *(v4f*)(V + hs * 2048 + row0 + q * 4) = f;
    }
}

// ---------------------------------------------------------------------------
// pair: block = 32 rows x 128 cols of out. 4 waves, each wave owns 8 rows
// (wave-uniform -> u reads are LDS b128 broadcasts). Thread: 8 rows x 2 cols,
// cols as float2 so the pk_{add,max,fma}_f32 path is expressible.
// ---------------------------------------------------------------------------
__global__ __launch_bounds__(256) void pair_kernel(
    const float* __restrict__ U, const float* __restrict__ V,
    const float* __restrict__ W2, const float* __restrict__ b2,
    float* __restrict__ out)
{
    __shared__ float u_lds[32 * HH];    // 8 KB   [r][h]  row-major
    __shared__ float vt[HH * 128];      // 32 KB  [h][c]  h-major
    __shared__ float w2_lds[HH];

    const int t = threadIdx.x;
    const int R = blockIdx.y * 32;
    const int C = blockIdx.x * 128;

    // stage tiles (both layouts match global layouts -> pure vectorized copies)
    {
        const v4f* Us = (const v4f*)(U + R * HH);
        v4f* Ud = (v4f*)u_lds;
        Ud[t]       = Us[t];
        Ud[t + 256] = Us[t + 256];
        const float* Vb = V + C;
        v4f* Vd = (v4f*)vt;
        #pragma unroll
        for (int i = 0; i < 8; ++i) {
            const int flat = t + i * 256;        // float4 index
            const int hh = flat >> 5;            // 32 float4 per h-row
            const int cc = flat & 31;
            Vd[flat] = *(const v4f*)(Vb + hh * 2048 + cc * 4);
        }
        if (t < HH) w2_lds[t] = W2[t];
    }
    __syncthreads();

    const int lane = t & 63;
    const int wv = t >> 6;
    const int r0 = wv * 8;        // wave-uniform rows
    const int c0 = lane * 2;

    v2f acc[8];
    #pragma unroll
    for (int i = 0; i < 8; ++i) acc[i] = 0.0f;

    const v2f vzero = 0.0f;
    #pragma unroll 2
    for (int h0 = 0; h0 < HH; h0 += 4) {
        const v4f w4 = *(const v4f*)&w2_lds[h0];               // broadcast
        const v2f vf0 = *(const v2f*)&vt[(h0 + 0) * 128 + c0]; // b64, bank-balanced
        const v2f vf1 = *(const v2f*)&vt[(h0 + 1) * 128 + c0];
        const v2f vf2 = *(const v2f*)&vt[(h0 + 2) * 128 + c0];
        const v2f vf3 = *(const v2f*)&vt[(h0 + 3) * 128 + c0];
        #pragma unroll
        for (int i = 0; i < 8; ++i) {
            const v4f uf = *(const v4f*)&u_lds[(r0 + i) * HH + h0];  // b128 broadcast
            v2f t0 = vf0 + uf.x; t0 = __builtin_elementwise_max(t0, vzero); acc[i] += t0 * w4.x;
            v2f t1 = vf1 + uf.y; t1 = __builtin_elementwise_max(t1, vzero); acc[i] += t1 * w4.y;
            v2f t2 = vf2 + uf.z; t2 = __builtin_elementwise_max(t2, vzero); acc[i] += t2 * w4.z;
            v2f t3 = vf3 + uf.w; t3 = __builtin_elementwise_max(t3, vzero); acc[i] += t3 * w4.w;
        }
    }

    const float b2v = *b2;
    #pragma unroll
    for (int i = 0; i < 8; ++i) {
        const v2f x = acc[i] + b2v;
        float2 st;
        st.x = 1.0f / (1.0f + __expf(-x.x));
        st.y = 1.0f / (1.0f + __expf(-x.y));
        *(float2*)(out + (size_t)(R + r0 + i) * 2048 + C + c0) = st;  // 512 B/wave/row
    }
}

extern "C" void kernel_launch(void* const* d_in, const int* in_sizes, int n_in,
                              void* d_out, int out_size, void* d_ws, size_t ws_size,
                              hipStream_t stream) {
    const float* ag = (const float*)d_in[0];   // [2048][256]
    const float* ab = (const float*)d_in[1];   // [2048][256]
    const float* W1 = (const float*)d_in[2];   // [512][64]
    const float* b1 = (const float*)d_in[3];   // [64]
    const float* W2 = (const float*)d_in[4];   // [64]
    const float* b2 = (const float*)d_in[5];   // [1]
    float* out = (float*)d_out;                // [2048][2048] fp32

    float* U = (float*)d_ws;                   // [2048][64] row-major (b1 folded)
    float* V = U + 2048 * HH;                  // [64][2048] h-major

    prep_kernel<<<256, 256, 0, stream>>>(ag, ab, W1, b1, U, V);
    pair_kernel<<<dim3(16, 64), 256, 0, stream>>>(U, V, W2, b2, out);
}